// Round 6
// baseline (120.214 us; speedup 1.0000x reference)
//
#include <hip/hip_runtime.h>
#include <hip/hip_bf16.h>

typedef __attribute__((ext_vector_type(8))) short bf16x8;
typedef __attribute__((ext_vector_type(8))) int i32x8;
typedef __attribute__((ext_vector_type(4))) float f32x4;
typedef unsigned int uint;

#define NROWS 8192
#define F_DIM 128
#define Q_DIM 64
#define KPAD  224   // 193 padded to 7*32
#define H_DIM 256

static __device__ inline unsigned short bf_bits(__hip_bfloat16 b) {
  unsigned short u; __builtin_memcpy(&u, &b, 2); return u;
}
static __device__ inline void split_hl(float v, unsigned short& h, unsigned short& l) {
  __hip_bfloat16 hb = __float2bfloat16(v);
  float hf = __bfloat162float(hb);
  __hip_bfloat16 lb = __float2bfloat16(v - hf);
  h = bf_bits(hb); l = bf_bits(lb);
}

// ---- fused prep: row norm -> xn8 (fp8), feats hi/lo planes, weight hi/lo
//      planes, zero cnt + out ----------------------------------------------
__global__ __launch_bounds__(256) void norm_prep_kernel(const float* __restrict__ x,
                                                        const float* __restrict__ q,
                                                        const float* __restrict__ W1,
                                                        const float* __restrict__ W2,
                                                        unsigned char* __restrict__ xn8,
                                                        unsigned short* __restrict__ fh,
                                                        unsigned short* __restrict__ fl,
                                                        unsigned short* __restrict__ w1h,
                                                        unsigned short* __restrict__ w1l,
                                                        unsigned short* __restrict__ w2h,
                                                        unsigned short* __restrict__ w2l,
                                                        int* __restrict__ cnt,
                                                        float* __restrict__ out) {
  int tid = threadIdx.x;
  if (blockIdx.x >= 2048) {   // weight prep
    int b = blockIdx.x - 2048;
    if (b < 256) {
      if (tid < KPAD) {
        unsigned short h = 0, l = 0;
        if (tid < 193) split_hl(W1[b * 193 + tid], h, l);
        w1h[b * KPAD + tid] = h;
        w1l[b * KPAD + tid] = l;
      }
    } else {
      int n = b - 256;
      unsigned short h, l;
      split_hl(W2[n * 256 + tid], h, l);
      w2h[n * 256 + tid] = h;
      w2l[n * 256 + tid] = l;
    }
    return;
  }
  int lane = tid & 63;
  int row = blockIdx.x * 4 + (tid >> 6);
  if (blockIdx.x < 32) {
    cnt[blockIdx.x * 256 + tid] = 0;
    out[blockIdx.x * 256 + tid] = 0.f;
  }
  const float2 v = *(const float2*)(x + (size_t)row * F_DIM + lane * 2);
  float s = v.x * v.x + v.y * v.y;
#pragma unroll
  for (int off = 32; off; off >>= 1) s += __shfl_xor(s, off);
  float inv = 1.0f / (sqrtf(s) + 1e-12f);
  int pk = __builtin_amdgcn_cvt_pk_fp8_f32(v.x * inv, v.y * inv, 0, 0);
  *(unsigned short*)(xn8 + (size_t)row * F_DIM + lane * 2) = (unsigned short)(pk & 0xffff);

  unsigned short h0, l0, h1, l1;
  unsigned short* fhr = fh + (size_t)row * KPAD;
  unsigned short* flr = fl + (size_t)row * KPAD;
  split_hl(v.x, h0, l0); split_hl(v.y, h1, l1);
  *(uint*)(fhr + lane * 2) = (uint)h0 | ((uint)h1 << 16);
  *(uint*)(flr + lane * 2) = (uint)l0 | ((uint)l1 << 16);
  if (lane < 32) {
    const float2 qv = *(const float2*)(q + (size_t)row * Q_DIM + lane * 2);
    split_hl(qv.x, h0, l0); split_hl(qv.y, h1, l1);
    *(uint*)(fhr + 128 + lane * 2) = (uint)h0 | ((uint)h1 << 16);
    *(uint*)(flr + 128 + lane * 2) = (uint)l0 | ((uint)l1 << 16);
  } else if (lane < 48) {
    *(uint*)(fhr + 192 + (lane - 32) * 2) = 0u;   // gf col + pad (gf patched in gemm1)
    *(uint*)(flr + 192 + (lane - 32) * 2) = 0u;
  }
}

// ---- Gram via MX-fp8 K=128 MFMA, fragments direct from global -------------
// Upper-triangle 128x128 tiles (2080 blocks), no LDS, no barriers.
__global__ __launch_bounds__(256) void gram8_kernel(const unsigned char* __restrict__ xn8,
                                                    int* __restrict__ cnt) {
  int tid = threadIdx.x;
  int lane = tid & 63;
  int wave = tid >> 6;
  int lr = lane & 15;
  int quad = lane >> 4;

  int t = blockIdx.x;
  int bi = (int)((129.0f - sqrtf(129.0f * 129.0f - 8.0f * (float)t)) * 0.5f);
  while ((bi + 1) * (129 - (bi + 1)) / 2 <= t) bi++;
  while (bi * (129 - bi) / 2 > t) bi--;
  int bj = bi + (t - bi * (129 - bi) / 2);
  int i_base = bi * 128 + (wave >> 1) * 64;
  int j_base = bj * 128 + (wave & 1) * 64;

  i32x8 a[4], b[4];
#pragma unroll
  for (int tt = 0; tt < 4; tt++) {
    const uint4* p = (const uint4*)(xn8 + (size_t)(i_base + tt * 16 + lr) * F_DIM + quad * 32);
    uint4 lo = p[0], hi = p[1];
    i32x8 f;
    f[0] = lo.x; f[1] = lo.y; f[2] = lo.z; f[3] = lo.w;
    f[4] = hi.x; f[5] = hi.y; f[6] = hi.z; f[7] = hi.w;
    a[tt] = f;
  }
#pragma unroll
  for (int tt = 0; tt < 4; tt++) {
    const uint4* p = (const uint4*)(xn8 + (size_t)(j_base + tt * 16 + lr) * F_DIM + quad * 32);
    uint4 lo = p[0], hi = p[1];
    i32x8 f;
    f[0] = lo.x; f[1] = lo.y; f[2] = lo.z; f[3] = lo.w;
    f[4] = hi.x; f[5] = hi.y; f[6] = hi.z; f[7] = hi.w;
    b[tt] = f;
  }

  f32x4 acc[4][4];
#pragma unroll
  for (int i = 0; i < 4; i++)
#pragma unroll
    for (int j = 0; j < 4; j++) acc[i][j] = (f32x4){0.f, 0.f, 0.f, 0.f};

#pragma unroll
  for (int tr = 0; tr < 4; tr++)
#pragma unroll
    for (int tc = 0; tc < 4; tc++)
      acc[tr][tc] = __builtin_amdgcn_mfma_scale_f32_16x16x128_f8f6f4(
          a[tr], b[tc], acc[tr][tc], 0, 0, 0, 0x7f7f7f7f, 0, 0x7f7f7f7f);

  bool diag_wave = (i_base == j_base);
  bool offdiag_block = (bi != bj);

  float mx = 0.f;
#pragma unroll
  for (int tr = 0; tr < 4; tr++)
#pragma unroll
    for (int tc = 0; tc < 4; tc++)
#pragma unroll
      for (int r = 0; r < 4; r++) {
        float v = acc[tr][tc][r];
        if (diag_wave && tr == tc && lr == quad * 4 + r) v = 0.f;
        mx = fmaxf(mx, fabsf(v));
      }
  if (__any(mx >= 0.9746f)) {
    for (int tr = 0; tr < 4; tr++)
      for (int tc = 0; tc < 4; tc++)
        for (int r = 0; r < 4; r++) {
          float v = acc[tr][tc][r];
          int row = i_base + tr * 16 + quad * 4 + r;
          int col = j_base + tc * 16 + lr;
          if (v * v >= 0.95f && row != col) {
            atomicAdd(&cnt[row], 1);
            if (offdiag_block) atomicAdd(&cnt[col], 1);
          }
        }
  }
}

// ---- hi/lo bf16 MFMA GEMM, fragments direct from global (no LDS) ----------
// Tile 64(m) x 64(n), 4 waves each 32x32. Grid (128, 4).
// MODE 1 (K=224): A=feats planes (gf col 192 patched from cnt at it==6),
//                 writes h1 hi/lo planes (relu + bias).
// MODE 2 (K=256): epilogue dot W3 (+b3 once) -> atomicAdd(out).
template <int K, int MODE>
__global__ __launch_bounds__(256) void gemm_mfma(const unsigned short* __restrict__ Ah,
                                                 const unsigned short* __restrict__ Al,
                                                 const unsigned short* __restrict__ Bh,
                                                 const unsigned short* __restrict__ Bl,
                                                 const float* __restrict__ bias,
                                                 unsigned short* __restrict__ Oh,
                                                 unsigned short* __restrict__ Ol,
                                                 const float* __restrict__ W3,
                                                 const float* __restrict__ b3,
                                                 const int* __restrict__ cnt,
                                                 float* __restrict__ out) {
  int tid = threadIdx.x;
  int lane = tid & 63;
  int wave = tid >> 6;
  int lr = lane & 15;
  int quad = lane >> 4;
  int mb = blockIdx.x * 64;
  int nb = blockIdx.y * 64;
  int wm = (wave & 1) * 32;
  int wn = (wave >> 1) * 32;

  // per-lane row bases (constant over K-loop)
  int rowA0 = mb + wm + lr, rowA1 = rowA0 + 16;
  int rowB0 = nb + wn + lr, rowB1 = rowB0 + 16;
  const unsigned short* pah0 = Ah + (size_t)rowA0 * K + quad * 8;
  const unsigned short* pah1 = Ah + (size_t)rowA1 * K + quad * 8;
  const unsigned short* pal0 = Al + (size_t)rowA0 * K + quad * 8;
  const unsigned short* pal1 = Al + (size_t)rowA1 * K + quad * 8;
  const unsigned short* pbh0 = Bh + (size_t)rowB0 * K + quad * 8;
  const unsigned short* pbh1 = Bh + (size_t)rowB1 * K + quad * 8;
  const unsigned short* pbl0 = Bl + (size_t)rowB0 * K + quad * 8;
  const unsigned short* pbl1 = Bl + (size_t)rowB1 * K + quad * 8;

  f32x4 acc[2][2];
#pragma unroll
  for (int i = 0; i < 2; i++)
#pragma unroll
    for (int j = 0; j < 2; j++) acc[i][j] = (f32x4){0.f, 0.f, 0.f, 0.f};

  constexpr int NIT = K / 32;
  bf16x8 cah[2], cal[2], cbh[2], cbl[2];
  cah[0] = *(const bf16x8*)(pah0); cah[1] = *(const bf16x8*)(pah1);
  cal[0] = *(const bf16x8*)(pal0); cal[1] = *(const bf16x8*)(pal1);
  cbh[0] = *(const bf16x8*)(pbh0); cbh[1] = *(const bf16x8*)(pbh1);
  cbl[0] = *(const bf16x8*)(pbl0); cbl[1] = *(const bf16x8*)(pbl1);

#pragma unroll
  for (int it = 0; it < NIT; ++it) {
    bf16x8 nah[2], nal[2], nbh[2], nbl[2];
    if (it + 1 < NIT) {
      int o = (it + 1) * 32;
      nah[0] = *(const bf16x8*)(pah0 + o); nah[1] = *(const bf16x8*)(pah1 + o);
      nal[0] = *(const bf16x8*)(pal0 + o); nal[1] = *(const bf16x8*)(pal1 + o);
      nbh[0] = *(const bf16x8*)(pbh0 + o); nbh[1] = *(const bf16x8*)(pbh1 + o);
      nbl[0] = *(const bf16x8*)(pbl0 + o); nbl[1] = *(const bf16x8*)(pbl1 + o);
    }
    if (MODE == 1 && it == 6 && quad == 0) {
      // col 192 = graph feature (element 0 of this fragment)
#pragma unroll
      for (int tt = 0; tt < 2; tt++) {
        float g = (float)cnt[rowA0 + tt * 16] * (1.0f / 8192.0f);
        unsigned short h, l;
        split_hl(g, h, l);
        cah[tt][0] = (short)h;
        cal[tt][0] = (short)l;
      }
    }
#pragma unroll
    for (int tt = 0; tt < 2; tt++)
#pragma unroll
      for (int tc = 0; tc < 2; tc++) {
        acc[tt][tc] = __builtin_amdgcn_mfma_f32_16x16x32_bf16(cah[tt], cbh[tc], acc[tt][tc], 0, 0, 0);
        acc[tt][tc] = __builtin_amdgcn_mfma_f32_16x16x32_bf16(cah[tt], cbl[tc], acc[tt][tc], 0, 0, 0);
        acc[tt][tc] = __builtin_amdgcn_mfma_f32_16x16x32_bf16(cal[tt], cbh[tc], acc[tt][tc], 0, 0, 0);
      }
#pragma unroll
    for (int i = 0; i < 2; i++) {
      cah[i] = nah[i]; cal[i] = nal[i];
      cbh[i] = nbh[i]; cbl[i] = nbl[i];
    }
  }

  if (MODE == 1) {
#pragma unroll
    for (int tc = 0; tc < 2; tc++) {
      int n = nb + wn + tc * 16 + lr;
      float bv = bias[n];
#pragma unroll
      for (int tt = 0; tt < 2; tt++) {
        int m0 = mb + wm + tt * 16 + quad * 4;
#pragma unroll
        for (int r = 0; r < 4; r++) {
          float v = fmaxf(acc[tt][tc][r] + bv, 0.f);
          unsigned short h, l;
          split_hl(v, h, l);
          Oh[(size_t)(m0 + r) * 256 + n] = h;
          Ol[(size_t)(m0 + r) * 256 + n] = l;
        }
      }
    }
  } else {
    // b3 added exactly once per row: wn==0 wave of the by==0 block
    float b3v = (blockIdx.y == 0 && wn == 0) ? b3[0] : 0.f;
#pragma unroll
    for (int tt = 0; tt < 2; tt++) {
      float s[4] = {0.f, 0.f, 0.f, 0.f};
#pragma unroll
      for (int tc = 0; tc < 2; tc++) {
        int n = nb + wn + tc * 16 + lr;
        float bv = bias[n];
        float w3v = W3[n];
#pragma unroll
        for (int r = 0; r < 4; r++) {
          float v = fmaxf(acc[tt][tc][r] + bv, 0.f);
          s[r] += v * w3v;
        }
      }
#pragma unroll
      for (int r = 0; r < 4; r++) {
        s[r] += __shfl_xor(s[r], 1);
        s[r] += __shfl_xor(s[r], 2);
        s[r] += __shfl_xor(s[r], 4);
        s[r] += __shfl_xor(s[r], 8);
      }
      if (lr == 0) {
        int m0 = mb + wm + tt * 16 + quad * 4;
#pragma unroll
        for (int r = 0; r < 4; r++) atomicAdd(&out[m0 + r], s[r] + b3v);
      }
    }
  }
}

extern "C" void kernel_launch(void* const* d_in, const int* in_sizes, int n_in,
                              void* d_out, int out_size, void* d_ws, size_t ws_size,
                              hipStream_t stream) {
  const float* x  = (const float*)d_in[0];
  const float* q  = (const float*)d_in[1];
  const float* W1 = (const float*)d_in[2];
  const float* b1 = (const float*)d_in[3];
  const float* W2 = (const float*)d_in[4];
  const float* b2 = (const float*)d_in[5];
  const float* W3 = (const float*)d_in[6];
  const float* b3 = (const float*)d_in[7];
  float* out = (float*)d_out;

  char* ws = (char*)d_ws;
  unsigned char*  xn8 = (unsigned char*)(ws);              // 1 MB
  int*            cnt = (int*)(ws + 0x100000);             // 32 KB
  unsigned short* fh  = (unsigned short*)(ws + 0x110000);  // 8192*224*2 = 3.5 MB
  unsigned short* fl  = (unsigned short*)(ws + 0x500000);  // 3.5 MB
  unsigned short* w1h = (unsigned short*)(ws + 0x8F0000);  // 112 KB
  unsigned short* w1l = (unsigned short*)(ws + 0x910000);  // 112 KB
  unsigned short* w2h = (unsigned short*)(ws + 0x930000);  // 128 KB
  unsigned short* w2l = (unsigned short*)(ws + 0x950000);  // 128 KB
  unsigned short* h1h = (unsigned short*)(ws + 0x970000);  // 8192*256*2 = 4 MB
  unsigned short* h1l = (unsigned short*)(ws + 0xD70000);  // 4 MB (end ~17.4 MB)

  norm_prep_kernel<<<dim3(2560), dim3(256), 0, stream>>>(x, q, W1, W2, xn8, fh, fl,
                                                         w1h, w1l, w2h, w2l, cnt, out);
  gram8_kernel<<<dim3(2080), dim3(256), 0, stream>>>(xn8, cnt);
  gemm_mfma<KPAD, 1><<<dim3(128, 4), dim3(256), 0, stream>>>(fh, fl, w1h, w1l, b1,
                                                             h1h, h1l, nullptr, nullptr, cnt, nullptr);
  gemm_mfma<256, 2><<<dim3(128, 4), dim3(256), 0, stream>>>(h1h, h1l, w2h, w2l, b2,
                                                            nullptr, nullptr, W3, b3, nullptr, out);
}

// Round 7
// 101.998 us; speedup vs baseline: 1.1786x; 1.1786x over previous
//
#include <hip/hip_runtime.h>
#include <hip/hip_bf16.h>

typedef __attribute__((ext_vector_type(8))) short bf16x8;
typedef __attribute__((ext_vector_type(8))) int i32x8;
typedef __attribute__((ext_vector_type(4))) float f32x4;
typedef unsigned int uint;

#define NROWS 8192
#define F_DIM 128
#define Q_DIM 64
#define KPAD  224   // 193 padded to 7*32
#define H_DIM 256

// pack fp32 -> (lo_bf16 << 16) | hi_bf16   (v ~= hi + lo, |err| <~ 2^-17 |v|)
static __device__ inline unsigned short bf_bits(__hip_bfloat16 b) {
  unsigned short u; __builtin_memcpy(&u, &b, 2); return u;
}
static __device__ inline uint packhl(float v) {
  __hip_bfloat16 h = __float2bfloat16(v);
  float hf = __bfloat162float(h);
  __hip_bfloat16 l = __float2bfloat16(v - hf);
  return ((uint)bf_bits(l) << 16) | (uint)bf_bits(h);
}

// ---- fused: row norm -> xn8(fp8 e4m3), feats packed hi/lo, zero cnt+out,
//      weight split+pack (blocks >= 2048) ----------------------------------
__global__ __launch_bounds__(256) void norm_prep_kernel(const float* __restrict__ x,
                                                        const float* __restrict__ q,
                                                        const float* __restrict__ W1,
                                                        const float* __restrict__ W2,
                                                        unsigned char* __restrict__ xn8,
                                                        uint* __restrict__ feats_p,
                                                        uint* __restrict__ W1P,
                                                        uint* __restrict__ W2P,
                                                        int* __restrict__ cnt,
                                                        float* __restrict__ out) {
  int tid = threadIdx.x;
  if (blockIdx.x >= 2048) {   // weight prep
    int b = blockIdx.x - 2048;
    if (b < 256) {
      if (tid < KPAD) W1P[b * KPAD + tid] = (tid < 193) ? packhl(W1[b * 193 + tid]) : 0u;
    } else {
      int n = b - 256;
      W2P[n * 256 + tid] = packhl(W2[n * 256 + tid]);
    }
    return;
  }
  int lane = tid & 63;
  int row = blockIdx.x * 4 + (tid >> 6);
  if (blockIdx.x < 32) {
    cnt[blockIdx.x * 256 + tid] = 0;
    out[blockIdx.x * 256 + tid] = 0.f;   // replaces the memset node
  }
  const float2 v = *(const float2*)(x + (size_t)row * F_DIM + lane * 2);
  float s = v.x * v.x + v.y * v.y;
#pragma unroll
  for (int off = 32; off; off >>= 1) s += __shfl_xor(s, off);
  float inv = 1.0f / (sqrtf(s) + 1e-12f);
  int pk = __builtin_amdgcn_cvt_pk_fp8_f32(v.x * inv, v.y * inv, 0, 0);
  *(unsigned short*)(xn8 + (size_t)row * F_DIM + lane * 2) = (unsigned short)(pk & 0xffff);

  uint* frow = feats_p + (size_t)row * KPAD;
  uint2 u;
  u.x = packhl(v.x); u.y = packhl(v.y);
  *(uint2*)(frow + lane * 2) = u;               // cols 0..127 (raw x)
  if (lane < 32) {
    const float2 qv = *(const float2*)(q + (size_t)row * Q_DIM + lane * 2);
    u.x = packhl(qv.x); u.y = packhl(qv.y);
    *(uint2*)(frow + 128 + lane * 2) = u;       // cols 128..191
  } else if (lane < 48) {
    uint2 z = {0u, 0u};
    *(uint2*)(frow + 192 + (lane - 32) * 2) = z; // cols 192..223 (gf + pad)
  }
}

// ---- Gram via MX-fp8 K=128 MFMA + threshold + row-count -------------------
__global__ __launch_bounds__(256) void gram8_kernel(const unsigned char* __restrict__ xn8,
                                                    int* __restrict__ cnt) {
  __shared__ char smem[32768];  // A 16KB + B 16KB; 128B rows, chunk ^ (row&7) swizzle
  int tid = threadIdx.x;
  int lane = tid & 63;
  int wave = tid >> 6;
  int lr = lane & 15;
  int quad = lane >> 4;

  int t = blockIdx.x;
  int bi = (int)((129.0f - sqrtf(129.0f * 129.0f - 8.0f * (float)t)) * 0.5f);
  while ((bi + 1) * (129 - (bi + 1)) / 2 <= t) bi++;
  while (bi * (129 - bi) / 2 > t) bi--;
  int bj = bi + (t - bi * (129 - bi) / 2);
  int i0 = bi * 128, j0 = bj * 128;

#pragma unroll
  for (int it = 0; it < 8; ++it) {
    int half = it >> 2;                    // 0 = A rows (i0), 1 = B rows (j0)
    int row = (it & 3) * 32 + (tid >> 3);
    int chunk = tid & 7;
    int grow = (half ? j0 : i0) + row;
    uint4 v = *(const uint4*)(xn8 + (size_t)grow * F_DIM + chunk * 16);
    *(uint4*)(smem + half * 16384 + row * 128 + ((chunk ^ (row & 7)) << 4)) = v;
  }
  __syncthreads();

  int wi = (wave >> 1) * 64, wj = (wave & 1) * 64;

  f32x4 acc[4][4];
#pragma unroll
  for (int i = 0; i < 4; i++)
#pragma unroll
    for (int j = 0; j < 4; j++) acc[i][j] = (f32x4){0.f, 0.f, 0.f, 0.f};

  i32x8 a[4], b[4];
#pragma unroll
  for (int tt = 0; tt < 4; tt++) {
    int r = wi + tt * 16 + lr;
    const char* base = smem + r * 128;
    uint4 lo = *(const uint4*)(base + (((2 * quad) ^ (r & 7)) << 4));
    uint4 hi = *(const uint4*)(base + (((2 * quad + 1) ^ (r & 7)) << 4));
    i32x8 f;
    f[0] = lo.x; f[1] = lo.y; f[2] = lo.z; f[3] = lo.w;
    f[4] = hi.x; f[5] = hi.y; f[6] = hi.z; f[7] = hi.w;
    a[tt] = f;
  }
#pragma unroll
  for (int tt = 0; tt < 4; tt++) {
    int r = wj + tt * 16 + lr;
    const char* base = smem + 16384 + r * 128;
    uint4 lo = *(const uint4*)(base + (((2 * quad) ^ (r & 7)) << 4));
    uint4 hi = *(const uint4*)(base + (((2 * quad + 1) ^ (r & 7)) << 4));
    i32x8 f;
    f[0] = lo.x; f[1] = lo.y; f[2] = lo.z; f[3] = lo.w;
    f[4] = hi.x; f[5] = hi.y; f[6] = hi.z; f[7] = hi.w;
    b[tt] = f;
  }

#pragma unroll
  for (int tr = 0; tr < 4; tr++)
#pragma unroll
    for (int tc = 0; tc < 4; tc++)
      acc[tr][tc] = __builtin_amdgcn_mfma_scale_f32_16x16x128_f8f6f4(
          a[tr], b[tc], acc[tr][tc], 0, 0, 0, 0x7f7f7f7f, 0, 0x7f7f7f7f);

  int i_base = i0 + wi, j_base = j0 + wj;
  bool diag_wave = (i_base == j_base);
  bool offdiag_block = (bi != bj);

  float mx = 0.f;
#pragma unroll
  for (int tr = 0; tr < 4; tr++)
#pragma unroll
    for (int tc = 0; tc < 4; tc++)
#pragma unroll
      for (int r = 0; r < 4; r++) {
        float v = acc[tr][tc][r];
        if (diag_wave && tr == tc && lr == quad * 4 + r) v = 0.f;
        mx = fmaxf(mx, fabsf(v));
      }
  if (__any(mx >= 0.9746f)) {
    for (int tr = 0; tr < 4; tr++)
      for (int tc = 0; tc < 4; tc++)
        for (int r = 0; r < 4; r++) {
          float v = acc[tr][tc][r];
          int row = i_base + tr * 16 + quad * 4 + r;
          int col = j_base + tc * 16 + lr;
          if (v * v >= 0.95f && row != col) {
            atomicAdd(&cnt[row], 1);
            if (offdiag_block) atomicAdd(&cnt[col], 1);
          }
        }
  }
}

// ---- hi/lo bf16 MFMA GEMM -------------------------------------------------
// MODE 1 (K=224): A=feats (col 192 injected from cnt), Out = packed relu.
// MODE 2 (K=256): epilogue dot W3 (+b3 once, by==0 && wn==0) -> atomicAdd.
template <int K, int MODE>
__global__ __launch_bounds__(256) void gemm_mfma(const uint* __restrict__ A,
                                                 const uint* __restrict__ Bp,
                                                 const float* __restrict__ bias,
                                                 uint* __restrict__ Out,
                                                 const float* __restrict__ W3,
                                                 const float* __restrict__ b3,
                                                 const int* __restrict__ cnt,
                                                 float* __restrict__ out) {
  __shared__ short Ahi[128 * 40];
  __shared__ short Alo[128 * 40];
  __shared__ short Bhi[64 * 40];
  __shared__ short Blo[64 * 40];

  int tid = threadIdx.x;
  int lane = tid & 63;
  int wave = tid >> 6;
  int lr = lane & 15;
  int quad = lane >> 4;
  int mb = blockIdx.x * 128;
  int nb = blockIdx.y * 64;
  int wm = (wave & 1) * 64;
  int wn = (wave >> 1) * 32;

  int a_row = tid >> 3;
  int a_c4 = (tid & 7) * 4;

  // cnt -> graph-feature column (col 192), loaded up-front (gemm1 only)
  uint gf[4];
  if (MODE == 1 && a_c4 == 0) {
#pragma unroll
    for (int i = 0; i < 4; i++)
      gf[i] = packhl((float)cnt[mb + a_row + i * 32] * (1.0f / 8192.0f));
  }

  f32x4 acc[4][2];
#pragma unroll
  for (int i = 0; i < 4; i++)
#pragma unroll
    for (int j = 0; j < 2; j++) acc[i][j] = (f32x4){0.f, 0.f, 0.f, 0.f};

  constexpr int NIT = K / 32;
  uint4 ar[4], br[2];

#pragma unroll
  for (int i = 0; i < 4; i++)
    ar[i] = *(const uint4*)(A + (size_t)(mb + a_row + i * 32) * K + a_c4);
#pragma unroll
  for (int i = 0; i < 2; i++)
    br[i] = *(const uint4*)(Bp + (size_t)(nb + a_row + i * 32) * K + a_c4);

  for (int it = 0; it < NIT; ++it) {
    if (MODE == 1 && it == 6 && a_c4 == 0) {
#pragma unroll
      for (int i = 0; i < 4; i++) ar[i].x = gf[i];   // col 192
    }
    __syncthreads();
#pragma unroll
    for (int i = 0; i < 4; i++) {
      int r = a_row + i * 32;
      uint h01 = (ar[i].x & 0xffffu) | (ar[i].y << 16);
      uint h23 = (ar[i].z & 0xffffu) | (ar[i].w << 16);
      uint l01 = (ar[i].x >> 16) | (ar[i].y & 0xffff0000u);
      uint l23 = (ar[i].z >> 16) | (ar[i].w & 0xffff0000u);
      *(uint2*)&Ahi[r * 40 + a_c4] = (uint2){h01, h23};
      *(uint2*)&Alo[r * 40 + a_c4] = (uint2){l01, l23};
    }
#pragma unroll
    for (int i = 0; i < 2; i++) {
      int r = a_row + i * 32;
      uint h01 = (br[i].x & 0xffffu) | (br[i].y << 16);
      uint h23 = (br[i].z & 0xffffu) | (br[i].w << 16);
      uint l01 = (br[i].x >> 16) | (br[i].y & 0xffff0000u);
      uint l23 = (br[i].z >> 16) | (br[i].w & 0xffff0000u);
      *(uint2*)&Bhi[r * 40 + a_c4] = (uint2){h01, h23};
      *(uint2*)&Blo[r * 40 + a_c4] = (uint2){l01, l23};
    }
    __syncthreads();

    if (it + 1 < NIT) {
      int k0 = (it + 1) * 32;
#pragma unroll
      for (int i = 0; i < 4; i++)
        ar[i] = *(const uint4*)(A + (size_t)(mb + a_row + i * 32) * K + k0 + a_c4);
#pragma unroll
      for (int i = 0; i < 2; i++)
        br[i] = *(const uint4*)(Bp + (size_t)(nb + a_row + i * 32) * K + k0 + a_c4);
    }

    bf16x8 ahi[4], alo[4], bhi[2], blo[2];
#pragma unroll
    for (int tt = 0; tt < 4; tt++) {
      int r = wm + tt * 16 + lr;
      ahi[tt] = *(const bf16x8*)&Ahi[r * 40 + quad * 8];
      alo[tt] = *(const bf16x8*)&Alo[r * 40 + quad * 8];
    }
#pragma unroll
    for (int tc = 0; tc < 2; tc++) {
      int r = wn + tc * 16 + lr;
      bhi[tc] = *(const bf16x8*)&Bhi[r * 40 + quad * 8];
      blo[tc] = *(const bf16x8*)&Blo[r * 40 + quad * 8];
    }
#pragma unroll
    for (int tt = 0; tt < 4; tt++)
#pragma unroll
      for (int tc = 0; tc < 2; tc++) {
        acc[tt][tc] = __builtin_amdgcn_mfma_f32_16x16x32_bf16(ahi[tt], bhi[tc], acc[tt][tc], 0, 0, 0);
        acc[tt][tc] = __builtin_amdgcn_mfma_f32_16x16x32_bf16(ahi[tt], blo[tc], acc[tt][tc], 0, 0, 0);
        acc[tt][tc] = __builtin_amdgcn_mfma_f32_16x16x32_bf16(alo[tt], bhi[tc], acc[tt][tc], 0, 0, 0);
      }
  }

  if (MODE == 1) {
#pragma unroll
    for (int tc = 0; tc < 2; tc++) {
      int n = nb + wn + tc * 16 + lr;
      float bv = bias[n];
#pragma unroll
      for (int tt = 0; tt < 4; tt++) {
        int m0 = mb + wm + tt * 16 + quad * 4;
#pragma unroll
        for (int r = 0; r < 4; r++) {
          float v = fmaxf(acc[tt][tc][r] + bv, 0.f);
          Out[(size_t)(m0 + r) * 256 + n] = packhl(v);
        }
      }
    }
  } else {
    // b3 added exactly once per row: only the wn==0 wave of the by==0 block
    float b3v = (blockIdx.y == 0 && wn == 0) ? b3[0] : 0.f;
#pragma unroll
    for (int tt = 0; tt < 4; tt++) {
      float s[4] = {0.f, 0.f, 0.f, 0.f};
#pragma unroll
      for (int tc = 0; tc < 2; tc++) {
        int n = nb + wn + tc * 16 + lr;
        float bv = bias[n];
        float w3v = W3[n];
#pragma unroll
        for (int r = 0; r < 4; r++) {
          float v = fmaxf(acc[tt][tc][r] + bv, 0.f);
          s[r] += v * w3v;
        }
      }
#pragma unroll
      for (int r = 0; r < 4; r++) {
        s[r] += __shfl_xor(s[r], 1);
        s[r] += __shfl_xor(s[r], 2);
        s[r] += __shfl_xor(s[r], 4);
        s[r] += __shfl_xor(s[r], 8);
      }
      if (lr == 0) {
        int m0 = mb + wm + tt * 16 + quad * 4;
#pragma unroll
        for (int r = 0; r < 4; r++) atomicAdd(&out[m0 + r], s[r] + b3v);
      }
    }
  }
}

extern "C" void kernel_launch(void* const* d_in, const int* in_sizes, int n_in,
                              void* d_out, int out_size, void* d_ws, size_t ws_size,
                              hipStream_t stream) {
  const float* x  = (const float*)d_in[0];
  const float* q  = (const float*)d_in[1];
  const float* W1 = (const float*)d_in[2];
  const float* b1 = (const float*)d_in[3];
  const float* W2 = (const float*)d_in[4];
  const float* b2 = (const float*)d_in[5];
  const float* W3 = (const float*)d_in[6];
  const float* b3 = (const float*)d_in[7];
  float* out = (float*)d_out;

  char* ws = (char*)d_ws;
  unsigned char* xn8 = (unsigned char*)(ws);         // 1 MB
  int*  cnt     = (int*)(ws + 0x100000);             // 32 KB
  uint* W1P     = (uint*)(ws + 0x110000);            // 224 KB
  uint* W2P     = (uint*)(ws + 0x150000);            // 256 KB
  uint* feats_p = (uint*)(ws + 0x190000);            // 7.3 MB
  uint* h1p     = (uint*)(ws + 0x890000);            // 8 MB

  norm_prep_kernel<<<dim3(2560), dim3(256), 0, stream>>>(x, q, W1, W2, xn8, feats_p, W1P, W2P, cnt, out);
  gram8_kernel<<<dim3(2080), dim3(256), 0, stream>>>(xn8, cnt);
  gemm_mfma<KPAD, 1><<<dim3(64, 4), dim3(256), 0, stream>>>(feats_p, W1P, b1, h1p, nullptr, nullptr, cnt, nullptr);
  gemm_mfma<256, 2><<<dim3(64, 4), dim3(256), 0, stream>>>(h1p, W2P, b2, nullptr, W3, b3, nullptr, out);
}

// Round 8
// 98.676 us; speedup vs baseline: 1.2183x; 1.0337x over previous
//
#include <hip/hip_runtime.h>
#include <hip/hip_bf16.h>

typedef __attribute__((ext_vector_type(8))) short bf16x8;
typedef __attribute__((ext_vector_type(8))) int i32x8;
typedef __attribute__((ext_vector_type(4))) float f32x4;
typedef unsigned int uint;

#define NROWS 8192
#define F_DIM 128
#define Q_DIM 64
#define KPAD  224   // 193 padded to 7*32
#define H_DIM 256

static __device__ inline unsigned short bf_bits(__hip_bfloat16 b) {
  unsigned short u; __builtin_memcpy(&u, &b, 2); return u;
}
static __device__ inline uint packhl(float v) {
  __hip_bfloat16 h = __float2bfloat16(v);
  float hf = __bfloat162float(h);
  __hip_bfloat16 l = __float2bfloat16(v - hf);
  return ((uint)bf_bits(l) << 16) | (uint)bf_bits(h);
}
static __device__ inline void split_hl(float v, unsigned short& h, unsigned short& l) {
  __hip_bfloat16 hb = __float2bfloat16(v);
  float hf = __bfloat162float(hb);
  __hip_bfloat16 lb = __float2bfloat16(v - hf);
  h = bf_bits(hb); l = bf_bits(lb);
}

union uu { uint4 u; bf16x8 v; };

// ---- prep: row norm -> xn8(fp8 e4m3), zero cnt, weight split+pack ---------
__global__ __launch_bounds__(256) void norm_prep_kernel(const float* __restrict__ x,
                                                        const float* __restrict__ W1,
                                                        const float* __restrict__ W2,
                                                        unsigned char* __restrict__ xn8,
                                                        uint* __restrict__ W1P,
                                                        uint* __restrict__ W2P,
                                                        int* __restrict__ cnt) {
  int tid = threadIdx.x;
  if (blockIdx.x >= 2048) {   // weight prep
    int b = blockIdx.x - 2048;
    if (b < 256) {
      if (tid < KPAD) W1P[b * KPAD + tid] = (tid < 193) ? packhl(W1[b * 193 + tid]) : 0u;
    } else {
      int n = b - 256;
      W2P[n * 256 + tid] = packhl(W2[n * 256 + tid]);
    }
    return;
  }
  int lane = tid & 63;
  int row = blockIdx.x * 4 + (tid >> 6);
  if (blockIdx.x < 32) cnt[blockIdx.x * 256 + tid] = 0;
  const float2 v = *(const float2*)(x + (size_t)row * F_DIM + lane * 2);
  float s = v.x * v.x + v.y * v.y;
#pragma unroll
  for (int off = 32; off; off >>= 1) s += __shfl_xor(s, off);
  float inv = 1.0f / (sqrtf(s) + 1e-12f);
  int pk = __builtin_amdgcn_cvt_pk_fp8_f32(v.x * inv, v.y * inv, 0, 0);
  *(unsigned short*)(xn8 + (size_t)row * F_DIM + lane * 2) = (unsigned short)(pk & 0xffff);
}

// ---- Gram via MX-fp8 K=128 MFMA + threshold + row-count -------------------
__global__ __launch_bounds__(256) void gram8_kernel(const unsigned char* __restrict__ xn8,
                                                    int* __restrict__ cnt) {
  __shared__ char smem[32768];  // A 16KB + B 16KB; 128B rows, chunk ^ (row&7) swizzle
  int tid = threadIdx.x;
  int lane = tid & 63;
  int wave = tid >> 6;
  int lr = lane & 15;
  int quad = lane >> 4;

  int t = blockIdx.x;
  int bi = (int)((129.0f - sqrtf(129.0f * 129.0f - 8.0f * (float)t)) * 0.5f);
  while ((bi + 1) * (129 - (bi + 1)) / 2 <= t) bi++;
  while (bi * (129 - bi) / 2 > t) bi--;
  int bj = bi + (t - bi * (129 - bi) / 2);
  int i0 = bi * 128, j0 = bj * 128;

#pragma unroll
  for (int it = 0; it < 8; ++it) {
    int half = it >> 2;                    // 0 = A rows (i0), 1 = B rows (j0)
    int row = (it & 3) * 32 + (tid >> 3);
    int chunk = tid & 7;
    int grow = (half ? j0 : i0) + row;
    uint4 v = *(const uint4*)(xn8 + (size_t)grow * F_DIM + chunk * 16);
    *(uint4*)(smem + half * 16384 + row * 128 + ((chunk ^ (row & 7)) << 4)) = v;
  }
  __syncthreads();

  int wi = (wave >> 1) * 64, wj = (wave & 1) * 64;

  f32x4 acc[4][4];
#pragma unroll
  for (int i = 0; i < 4; i++)
#pragma unroll
    for (int j = 0; j < 4; j++) acc[i][j] = (f32x4){0.f, 0.f, 0.f, 0.f};

  i32x8 a[4], b[4];
#pragma unroll
  for (int tt = 0; tt < 4; tt++) {
    int r = wi + tt * 16 + lr;
    const char* base = smem + r * 128;
    uint4 lo = *(const uint4*)(base + (((2 * quad) ^ (r & 7)) << 4));
    uint4 hi = *(const uint4*)(base + (((2 * quad + 1) ^ (r & 7)) << 4));
    i32x8 f;
    f[0] = lo.x; f[1] = lo.y; f[2] = lo.z; f[3] = lo.w;
    f[4] = hi.x; f[5] = hi.y; f[6] = hi.z; f[7] = hi.w;
    a[tt] = f;
  }
#pragma unroll
  for (int tt = 0; tt < 4; tt++) {
    int r = wj + tt * 16 + lr;
    const char* base = smem + 16384 + r * 128;
    uint4 lo = *(const uint4*)(base + (((2 * quad) ^ (r & 7)) << 4));
    uint4 hi = *(const uint4*)(base + (((2 * quad + 1) ^ (r & 7)) << 4));
    i32x8 f;
    f[0] = lo.x; f[1] = lo.y; f[2] = lo.z; f[3] = lo.w;
    f[4] = hi.x; f[5] = hi.y; f[6] = hi.z; f[7] = hi.w;
    b[tt] = f;
  }

#pragma unroll
  for (int tr = 0; tr < 4; tr++)
#pragma unroll
    for (int tc = 0; tc < 4; tc++)
      acc[tr][tc] = __builtin_amdgcn_mfma_scale_f32_16x16x128_f8f6f4(
          a[tr], b[tc], acc[tr][tc], 0, 0, 0, 0x7f7f7f7f, 0, 0x7f7f7f7f);

  int i_base = i0 + wi, j_base = j0 + wj;
  bool diag_wave = (i_base == j_base);
  bool offdiag_block = (bi != bj);

  float mx = 0.f;
#pragma unroll
  for (int tr = 0; tr < 4; tr++)
#pragma unroll
    for (int tc = 0; tc < 4; tc++)
#pragma unroll
      for (int r = 0; r < 4; r++) {
        float v = acc[tr][tc][r];
        if (diag_wave && tr == tc && lr == quad * 4 + r) v = 0.f;
        mx = fmaxf(mx, fabsf(v));
      }
  if (__any(mx >= 0.9746f)) {
    for (int tr = 0; tr < 4; tr++)
      for (int tc = 0; tc < 4; tc++)
        for (int r = 0; r < 4; r++) {
          float v = acc[tr][tc][r];
          int row = i_base + tr * 16 + quad * 4 + r;
          int col = j_base + tc * 16 + lr;
          if (v * v >= 0.95f && row != col) {
            atomicAdd(&cnt[row], 1);
            if (offdiag_block) atomicAdd(&cnt[col], 1);
          }
        }
  }
}

// ---- fused MLP: 32 rows/block, layer1 -> h1 in LDS -> layer2 -> W3 dot ----
// LDS (64 KB exactly): region0 = A hi/lo shorts [32][232]  UNION  H1 packed
// uints [32][256] (16B-chunk XOR swizzle); region1 = B packed uints [256][32]
// (16B-chunk XOR swizzle)  UNION  part[4][32] floats.
__global__ __launch_bounds__(256) void fused_mlp_kernel(const float* __restrict__ x,
                                                        const float* __restrict__ q,
                                                        const uint* __restrict__ W1P,
                                                        const uint* __restrict__ W2P,
                                                        const float* __restrict__ b1,
                                                        const float* __restrict__ b2,
                                                        const float* __restrict__ W3,
                                                        const float* __restrict__ b3,
                                                        const int* __restrict__ cnt,
                                                        float* __restrict__ out) {
  __shared__ char smem[65536];
  short* Ahs = (short*)smem;                 // [32][232] hi  (14848 B)
  short* Als = (short*)(smem + 14848);       // [32][232] lo
  uint*  H1  = (uint*)smem;                  // [32][256] packed, overlays A
  uint*  Bx  = (uint*)(smem + 32768);        // [256][32] packed
  float* part = (float*)(smem + 32768);      // [4][32], overlays Bx

  int tid = threadIdx.x;
  int lane = tid & 63;
  int wv = tid >> 6;
  int lr = lane & 15;
  int quad = lane >> 4;
  int mb = blockIdx.x * 32;

  // ---- A stage: feats[32][224] hi/lo from x, q, cnt ----
  {
    int r = tid >> 3;
    int c8 = (tid & 7) * 4;
#pragma unroll
    for (int it = 0; it < 7; ++it) {
      int col = it * 32 + c8;
      float4 v = {0.f, 0.f, 0.f, 0.f};
      if (it < 4)      v = *(const float4*)(x + (size_t)(mb + r) * F_DIM + col);
      else if (it < 6) v = *(const float4*)(q + (size_t)(mb + r) * Q_DIM + (col - 128));
      else if (c8 == 0) v.x = (float)cnt[mb + r] * (1.0f / 8192.0f);
      unsigned short h0, l0, h1, l1, h2, l2, h3, l3;
      split_hl(v.x, h0, l0); split_hl(v.y, h1, l1);
      split_hl(v.z, h2, l2); split_hl(v.w, h3, l3);
      *(uint2*)&Ahs[r * 232 + col] = (uint2){(uint)h0 | ((uint)h1 << 16), (uint)h2 | ((uint)h3 << 16)};
      *(uint2*)&Als[r * 232 + col] = (uint2){(uint)l0 | ((uint)l1 << 16), (uint)l2 | ((uint)l3 << 16)};
    }
  }

  f32x4 acc[2][4];
#pragma unroll
  for (int i = 0; i < 2; i++)
#pragma unroll
    for (int j = 0; j < 4; j++) acc[i][j] = (f32x4){0.f, 0.f, 0.f, 0.f};

  // ---- phase 1: h1 = relu(feats @ W1^T + b1), K = 224 ----
  for (int kc = 0; kc < 7; ++kc) {
    int k0 = kc * 32;
    __syncthreads();
#pragma unroll
    for (int i = 0; i < 8; ++i) {
      int flat = i * 256 + tid;
      int n = flat >> 3, j = flat & 7;
      uint4 w = *(const uint4*)(W1P + (size_t)n * KPAD + k0 + j * 4);
      *(uint4*)&Bx[n * 32 + ((j ^ (n & 7)) * 4)] = w;
    }
    __syncthreads();
    bf16x8 ah[2], al[2], bh[4], bl[4];
#pragma unroll
    for (int tt = 0; tt < 2; ++tt) {
      int row = tt * 16 + lr;
      ah[tt] = *(const bf16x8*)&Ahs[row * 232 + k0 + quad * 8];
      al[tt] = *(const bf16x8*)&Als[row * 232 + k0 + quad * 8];
    }
#pragma unroll
    for (int tc = 0; tc < 4; ++tc) {
      int n = wv * 64 + tc * 16 + lr;
      uint4 u0 = *(const uint4*)&Bx[n * 32 + (((quad * 2) ^ (n & 7)) * 4)];
      uint4 u1 = *(const uint4*)&Bx[n * 32 + (((quad * 2 + 1) ^ (n & 7)) * 4)];
      uu h, l;
      h.u.x = (u0.x & 0xffffu) | (u0.y << 16);
      h.u.y = (u0.z & 0xffffu) | (u0.w << 16);
      h.u.z = (u1.x & 0xffffu) | (u1.y << 16);
      h.u.w = (u1.z & 0xffffu) | (u1.w << 16);
      l.u.x = (u0.x >> 16) | (u0.y & 0xffff0000u);
      l.u.y = (u0.z >> 16) | (u0.w & 0xffff0000u);
      l.u.z = (u1.x >> 16) | (u1.y & 0xffff0000u);
      l.u.w = (u1.z >> 16) | (u1.w & 0xffff0000u);
      bh[tc] = h.v; bl[tc] = l.v;
    }
#pragma unroll
    for (int tt = 0; tt < 2; ++tt)
#pragma unroll
      for (int tc = 0; tc < 4; ++tc) {
        acc[tt][tc] = __builtin_amdgcn_mfma_f32_16x16x32_bf16(ah[tt], bh[tc], acc[tt][tc], 0, 0, 0);
        acc[tt][tc] = __builtin_amdgcn_mfma_f32_16x16x32_bf16(ah[tt], bl[tc], acc[tt][tc], 0, 0, 0);
        acc[tt][tc] = __builtin_amdgcn_mfma_f32_16x16x32_bf16(al[tt], bh[tc], acc[tt][tc], 0, 0, 0);
      }
  }

  __syncthreads();   // all A reads done before H1 overlays A
  // ---- phase-1 epilogue: relu+bias -> H1 (packed, swizzled) ----
#pragma unroll
  for (int tc = 0; tc < 4; ++tc) {
    int n = wv * 64 + tc * 16 + lr;
    float bv = b1[n];
    int g = n >> 2, jj = n & 3;
#pragma unroll
    for (int tt = 0; tt < 2; ++tt)
#pragma unroll
      for (int r = 0; r < 4; ++r) {
        int row = tt * 16 + quad * 4 + r;
        float v = fmaxf(acc[tt][tc][r] + bv, 0.f);
        H1[row * 256 + ((g ^ (row & 31)) * 4 + jj)] = packhl(v);
      }
  }
#pragma unroll
  for (int i = 0; i < 2; i++)
#pragma unroll
    for (int j = 0; j < 4; j++) acc[i][j] = (f32x4){0.f, 0.f, 0.f, 0.f};

  // ---- phase 2: h2 = relu(h1 @ W2^T + b2), K = 256 ----
  for (int kc = 0; kc < 8; ++kc) {
    int k0 = kc * 32;
    __syncthreads();
#pragma unroll
    for (int i = 0; i < 8; ++i) {
      int flat = i * 256 + tid;
      int n = flat >> 3, j = flat & 7;
      uint4 w = *(const uint4*)(W2P + (size_t)n * 256 + k0 + j * 4);
      *(uint4*)&Bx[n * 32 + ((j ^ (n & 7)) * 4)] = w;
    }
    __syncthreads();
    bf16x8 ah[2], al[2], bh[4], bl[4];
#pragma unroll
    for (int tt = 0; tt < 2; ++tt) {
      int row = tt * 16 + lr;
      int cb = kc * 8 + quad * 2;
      uint4 u0 = *(const uint4*)&H1[row * 256 + ((cb ^ (row & 31)) * 4)];
      uint4 u1 = *(const uint4*)&H1[row * 256 + (((cb + 1) ^ (row & 31)) * 4)];
      uu h, l;
      h.u.x = (u0.x & 0xffffu) | (u0.y << 16);
      h.u.y = (u0.z & 0xffffu) | (u0.w << 16);
      h.u.z = (u1.x & 0xffffu) | (u1.y << 16);
      h.u.w = (u1.z & 0xffffu) | (u1.w << 16);
      l.u.x = (u0.x >> 16) | (u0.y & 0xffff0000u);
      l.u.y = (u0.z >> 16) | (u0.w & 0xffff0000u);
      l.u.z = (u1.x >> 16) | (u1.y & 0xffff0000u);
      l.u.w = (u1.z >> 16) | (u1.w & 0xffff0000u);
      ah[tt] = h.v; al[tt] = l.v;
    }
#pragma unroll
    for (int tc = 0; tc < 4; ++tc) {
      int n = wv * 64 + tc * 16 + lr;
      uint4 u0 = *(const uint4*)&Bx[n * 32 + (((quad * 2) ^ (n & 7)) * 4)];
      uint4 u1 = *(const uint4*)&Bx[n * 32 + (((quad * 2 + 1) ^ (n & 7)) * 4)];
      uu h, l;
      h.u.x = (u0.x & 0xffffu) | (u0.y << 16);
      h.u.y = (u0.z & 0xffffu) | (u0.w << 16);
      h.u.z = (u1.x & 0xffffu) | (u1.y << 16);
      h.u.w = (u1.z & 0xffffu) | (u1.w << 16);
      l.u.x = (u0.x >> 16) | (u0.y & 0xffff0000u);
      l.u.y = (u0.z >> 16) | (u0.w & 0xffff0000u);
      l.u.z = (u1.x >> 16) | (u1.y & 0xffff0000u);
      l.u.w = (u1.z >> 16) | (u1.w & 0xffff0000u);
      bh[tc] = h.v; bl[tc] = l.v;
    }
#pragma unroll
    for (int tt = 0; tt < 2; ++tt)
#pragma unroll
      for (int tc = 0; tc < 4; ++tc) {
        acc[tt][tc] = __builtin_amdgcn_mfma_f32_16x16x32_bf16(ah[tt], bh[tc], acc[tt][tc], 0, 0, 0);
        acc[tt][tc] = __builtin_amdgcn_mfma_f32_16x16x32_bf16(ah[tt], bl[tc], acc[tt][tc], 0, 0, 0);
        acc[tt][tc] = __builtin_amdgcn_mfma_f32_16x16x32_bf16(al[tt], bh[tc], acc[tt][tc], 0, 0, 0);
      }
  }

  // ---- phase-2 epilogue: relu+bias, dot W3, cross-wave reduce, store ----
  float s[2][4];
#pragma unroll
  for (int tt = 0; tt < 2; ++tt)
#pragma unroll
    for (int r = 0; r < 4; ++r) s[tt][r] = 0.f;
#pragma unroll
  for (int tc = 0; tc < 4; ++tc) {
    int n = wv * 64 + tc * 16 + lr;
    float bv = b2[n];
    float w3 = W3[n];
#pragma unroll
    for (int tt = 0; tt < 2; ++tt)
#pragma unroll
      for (int r = 0; r < 4; ++r)
        s[tt][r] += fmaxf(acc[tt][tc][r] + bv, 0.f) * w3;
  }
#pragma unroll
  for (int tt = 0; tt < 2; ++tt)
#pragma unroll
    for (int r = 0; r < 4; ++r) {
      s[tt][r] += __shfl_xor(s[tt][r], 1);
      s[tt][r] += __shfl_xor(s[tt][r], 2);
      s[tt][r] += __shfl_xor(s[tt][r], 4);
      s[tt][r] += __shfl_xor(s[tt][r], 8);
    }
  __syncthreads();   // all Bx reads done before part overlays Bx
  if (lr == 0) {
#pragma unroll
    for (int tt = 0; tt < 2; ++tt)
#pragma unroll
      for (int r = 0; r < 4; ++r)
        part[wv * 32 + tt * 16 + quad * 4 + r] = s[tt][r];
  }
  __syncthreads();
  if (tid < 32)
    out[mb + tid] = part[tid] + part[32 + tid] + part[64 + tid] + part[96 + tid] + b3[0];
}

extern "C" void kernel_launch(void* const* d_in, const int* in_sizes, int n_in,
                              void* d_out, int out_size, void* d_ws, size_t ws_size,
                              hipStream_t stream) {
  const float* x  = (const float*)d_in[0];
  const float* q  = (const float*)d_in[1];
  const float* W1 = (const float*)d_in[2];
  const float* b1 = (const float*)d_in[3];
  const float* W2 = (const float*)d_in[4];
  const float* b2 = (const float*)d_in[5];
  const float* W3 = (const float*)d_in[6];
  const float* b3 = (const float*)d_in[7];
  float* out = (float*)d_out;

  char* ws = (char*)d_ws;
  unsigned char* xn8 = (unsigned char*)(ws);         // 1 MB
  int*  cnt = (int*)(ws + 0x100000);                 // 32 KB
  uint* W1P = (uint*)(ws + 0x110000);                // 224 KB
  uint* W2P = (uint*)(ws + 0x150000);                // 256 KB

  norm_prep_kernel<<<dim3(2560), dim3(256), 0, stream>>>(x, W1, W2, xn8, W1P, W2P, cnt);
  gram8_kernel<<<dim3(2080), dim3(256), 0, stream>>>(xn8, cnt);
  fused_mlp_kernel<<<dim3(256), dim3(256), 0, stream>>>(x, q, W1P, W2P, b1, b2, W3, b3, cnt, out);
}